// Round 5
// baseline (570.274 us; speedup 1.0000x reference)
//
#include <hip/hip_runtime.h>

#define Bn 32
#define Nn 24564
#define MAXB 200
#define TSEL 8192
#define NBIN 2048
#define NCHUNK (Bn * 384)

typedef unsigned long long u64;
typedef unsigned int u32;

// -------- accurate double exp (rel err ~6e-15) -- proven bit-stable R2-R4
__device__ inline double fast_exp_d(double x) {
  const double LOG2E = 1.4426950408889634074;
  const double LN2   = 0.69314718055994530942;
  double t = x * LOG2E;
  double fi = floor(t + 0.5);
  double f = (t - fi) * LN2;
  double p = 2.505210838544172e-8;
  p = p * f + 2.755731922398589e-7;
  p = p * f + 2.7557319223985893e-6;
  p = p * f + 2.48015873015873e-5;
  p = p * f + 1.984126984126984e-4;
  p = p * f + 1.3888888888888889e-3;
  p = p * f + 8.333333333333333e-3;
  p = p * f + 4.1666666666666664e-2;
  p = p * f + 1.6666666666666666e-1;
  p = p * f + 0.5;
  p = p * f + 1.0;
  p = p * f + 1.0;
  long long e = (long long)fi;
  return p * __longlong_as_double((e + 1023LL) << 52);
}

__device__ inline double clip01(double v) {
  return v < 0.0 ? 0.0 : (v > 1.0 ? 1.0 : v);
}

// ============================================================
// kk1: persistent, software-pipelined f32 scoring -> bin + histogram
// ============================================================
__global__ __launch_bounds__(256) void kk1_score(const float* __restrict__ logits,
                                                 u32* __restrict__ binA,
                                                 int* __restrict__ hist) {
  __shared__ float lds[64 * 85];
  const int tid = threadIdx.x;
  float4 f[6];
  int c = blockIdx.x;
  int nf4;
  {
    const int b = c / 384, n0 = (c % 384) << 6;
    int cnt = Nn - n0; cnt = cnt > 64 ? 64 : cnt;
    nf4 = (cnt * 85) >> 2;
    const float4* src = (const float4*)(logits + ((size_t)b * Nn + n0) * 85);
    #pragma unroll
    for (int i = 0; i < 6; ++i) { int idx = i * 256 + tid; if (idx < nf4) f[i] = src[idx]; }
  }
  while (c < NCHUNK) {
    const int b = c / 384, n0 = (c % 384) << 6;
    int cnt = Nn - n0; cnt = cnt > 64 ? 64 : cnt;
    __syncthreads();                       // prev compute done reading LDS
    #pragma unroll
    for (int i = 0; i < 6; ++i) { int idx = i * 256 + tid; if (idx < nf4) ((float4*)lds)[idx] = f[i]; }
    __syncthreads();                       // LDS ready
    const int cn = c + (int)gridDim.x;
    if (cn < NCHUNK) {                     // issue next chunk's loads NOW (hidden under compute)
      const int b2 = cn / 384, n02 = (cn % 384) << 6;
      int cnt2 = Nn - n02; cnt2 = cnt2 > 64 ? 64 : cnt2;
      nf4 = (cnt2 * 85) >> 2;
      const float4* src = (const float4*)(logits + ((size_t)b2 * Nn + n02) * 85);
      #pragma unroll
      for (int i = 0; i < 6; ++i) { int idx = i * 256 + tid; if (idx < nf4) f[i] = src[idx]; }
    }
    // ---- compute current chunk ----
    const int g = tid >> 2, s = tid & 3;
    if (g < cnt) {
      const float* row = lds + g * 85;
      float mx = -1e30f; int ai = 1000;
      for (int cc = s; cc < 81; cc += 4) {
        float v = row[4 + cc];
        if (v > mx) { mx = v; ai = cc; }
      }
      #pragma unroll
      for (int d = 1; d <= 2; d <<= 1) {
        float om = __shfl_xor(mx, d);
        int oi = __shfl_xor(ai, d);
        if (om > mx || (om == mx && oi < ai)) { mx = om; ai = oi; }
      }
      float sum = 0.f;
      for (int cc = s; cc < 81; cc += 4) sum += __expf(row[4 + cc] - mx);
      sum += __shfl_xor(sum, 1);
      sum += __shfl_xor(sum, 2);
      if (s == 0) {
        float sc = 1.0f / sum;
        u32 outv = 0xFFFFFFFFu;
        if (ai != 0 && sc >= 0.00985f) {   // margin; kk4 rechecks exactly
          u32 sb = __float_as_uint(sc);
          int e3 = (int)(sb >> 23) - 119;
          int bin_desc = (e3 << 8) | (int)((sb >> 15) & 0xFF);
          int bin_a = 2047 - bin_desc;
          bin_a = bin_a < 0 ? 0 : bin_a;
          outv = (u32)bin_a;
          atomicAdd(&hist[b * NBIN + bin_a], 1);
        }
        binA[(size_t)b * Nn + n0 + g] = outv;
      }
    }
    c = cn;
  }
}

// ============================================================
// kk2: per-image cutoff bin C = largest bin with inclusive cumsum <= TSEL
// ============================================================
__global__ __launch_bounds__(256) void kk2_cutoff(const int* __restrict__ hist,
                                                  int* __restrict__ Cg) {
  __shared__ int part[256];
  __shared__ int gincl[64];
  __shared__ int sC;
  const int b = blockIdx.x;
  const int tid = threadIdx.x;
  int h[8];
  int ps = 0;
  #pragma unroll
  for (int q = 0; q < 8; ++q) { h[q] = hist[b * NBIN + tid * 8 + q]; ps += h[q]; }
  part[tid] = ps;
  if (tid == 0) sC = -1;
  __syncthreads();
  if (tid < 64) {
    int s4 = part[tid * 4] + part[tid * 4 + 1] + part[tid * 4 + 2] + part[tid * 4 + 3];
    int run = s4;
    for (int d = 1; d < 64; d <<= 1) {
      int v = __shfl_up(run, d);
      if (tid >= d) run += v;
    }
    gincl[tid] = run;
  }
  __syncthreads();
  int base = (tid >> 2) ? gincl[(tid >> 2) - 1] : 0;
  for (int q = (tid & ~3); q < tid; ++q) base += part[q];
  int run = base, localC = -1;
  #pragma unroll
  for (int q = 0; q < 8; ++q) {
    run += h[q];
    if (run <= TSEL) localC = tid * 8 + q;
  }
  if (localC >= 0) atomicMax(&sC, localC);
  __syncthreads();
  if (tid == 0) Cg[b] = sC;
}

// ============================================================
// kk3: grid-wide ballot compaction of anchors with bin <= C into clist
// ============================================================
__global__ __launch_bounds__(256) void kk3_compact(const u32* __restrict__ binA,
                                                   const int* __restrict__ Cg,
                                                   int* __restrict__ cntG,
                                                   int* __restrict__ clist) {
  const int tid = threadIdx.x;
  const int bx = blockIdx.x;
  const int b = bx / 96;
  const int i = ((bx % 96) << 8) + tid;
  const u32 C = (u32)Cg[b];
  bool pred = false;
  if (i < Nn) pred = (binA[(size_t)b * Nn + i] <= C);
  u64 m = __ballot(pred);
  int lane = tid & 63;
  int base = 0;
  if (lane == 0 && m) base = atomicAdd(&cntG[b], (int)__popcll(m));
  base = __shfl(base, 0);
  if (pred) {
    int off = (int)__popcll(m & ((1ULL << lane) - 1ULL));
    int p = base + off;
    if (p < TSEL) clist[b * TSEL + p] = i;
  }
}

// ============================================================
// kk4: exact f64 rescore, LDS-staged coalesced rows, static reg arrays.
// Bit-identical reduction order to the R2-proven kernel.
// ============================================================
__global__ __launch_bounds__(256) void kk4_rescore(const float* __restrict__ logits,
                                                   const float* __restrict__ anchors,
                                                   const int* __restrict__ clist,
                                                   const int* __restrict__ cntG,
                                                   double* __restrict__ boxesd,
                                                   int* __restrict__ clsd,
                                                   u64* __restrict__ ekeys) {
  __shared__ float buf[64 * 89];           // stride 89: odd vs 32 banks
  __shared__ int sRow[64];
  const int tid = threadIdx.x;
  const int b = blockIdx.x >> 7;
  const int blk = blockIdx.x & 127;
  int cnt = cntG[b]; cnt = cnt > TSEL ? TSEL : cnt;
  const int slot0 = blk << 6;
  if (tid < 64) {
    int slot = slot0 + tid;
    sRow[tid] = (slot < cnt) ? clist[b * TSEL + slot] : -1;
  }
  __syncthreads();
  for (int i = tid; i < 64 * 85; i += 256) {
    int r = i / 85, o = i - r * 85;        // compiler magic-mul, exact
    int n = sRow[r];
    if (n >= 0) buf[r * 89 + o] = logits[((size_t)b * Nn + n) * 85 + o];
  }
  __syncthreads();
  const int g = tid >> 2, s = tid & 3;
  const int slot = slot0 + g;
  const int n = sRow[g];
  u64 K = ~0ULL;
  if (n >= 0) {
    const float* row = buf + g * 89;
    float rv[21];
    float mx = -1e30f; int ai = 1000;
    #pragma unroll
    for (int q = 0; q < 21; ++q) {         // static indices -> registers
      int cc = s + 4 * q;
      float v = (cc < 81) ? row[4 + cc] : -1e30f;
      rv[q] = v;
      if (cc < 81 && v > mx) { mx = v; ai = cc; }
    }
    #pragma unroll
    for (int d = 1; d <= 2; d <<= 1) {
      float om = __shfl_xor(mx, d);
      int oi = __shfl_xor(ai, d);
      if (om > mx || (om == mx && oi < ai)) { mx = om; ai = oi; }
    }
    double sum = 0.0;
    #pragma unroll
    for (int q = 0; q < 21; ++q) {
      if (s + 4 * q < 81) sum += fast_exp_d((double)rv[q] - (double)mx);
    }
    sum += __shfl_xor(sum, 1);
    sum += __shfl_xor(sum, 2);
    if (s == 0) {
      double score = 1.0 / sum;
      if (ai != 0 && score >= 0.01) {
        float4 a4 = reinterpret_cast<const float4*>(anchors)[n];
        double ax1 = a4.x, ay1 = a4.y, ax2 = a4.z, ay2 = a4.w;
        double cx = (ax2 + ax1) * 0.5, cy = (ay2 + ay1) * 0.5;
        double ww = ax2 - ax1, hh = ay2 - ay1;
        double ctrx = (double)row[0] * ww + cx;
        double ctry = (double)row[1] * hh + cy;
        double szx = fast_exp_d((double)row[2]) * ww;
        double szy = fast_exp_d((double)row[3]) * hh;
        double* bp = boxesd + (size_t)(b * Nn + n) * 4;
        bp[0] = clip01(ctrx - szx * 0.5);
        bp[1] = clip01(ctry - szy * 0.5);
        bp[2] = clip01(ctrx + szx * 0.5);
        bp[3] = clip01(ctry + szy * 0.5);
        clsd[b * Nn + n] = ai;
        u64 sb = (u64)__double_as_longlong(score);
        u64 e4 = (sb >> 52) - 1015ULL;
        u64 mant45 = (sb & ((1ULL << 52) - 1)) >> 7;
        u64 flip = (~((e4 << 45) | mant45)) & ((1ULL << 49) - 1);
        K = (flip << 15) | (u64)n;
      }
    }
  }
  if (s == 0) ekeys[b * TSEL + slot] = K;
}

// ============================================================
// kk5: LDS bitonic sort of 8192 exact keys + greedy NMS + outputs
// ============================================================
__global__ __launch_bounds__(1024) void kk5_nms(const u64* __restrict__ ekeys,
                                                const double* __restrict__ boxesd,
                                                const int* __restrict__ clsd,
                                                float* __restrict__ out) {
  __shared__ u64 sel[TSEL];
  __shared__ double selBox[MAXB][4];
  __shared__ double selArea[MAXB];
  __shared__ float selScore[MAXB];
  __shared__ int selIdx[MAXB];
  __shared__ int sS;
  const int b = blockIdx.x;
  const int tid = threadIdx.x;

  for (int i = tid; i < TSEL; i += 1024) sel[i] = ekeys[b * TSEL + i];
  __syncthreads();

  for (int k = 2; k <= TSEL; k <<= 1) {
    for (int j = k >> 1; j >= 1; j >>= 1) {
      for (int p = tid; p < (TSEL / 2); p += 1024) {
        int l = ((p & ~(j - 1)) << 1) | (p & (j - 1));
        int r = l | j;
        bool up = ((l & k) == 0);
        u64 a = sel[l], bb = sel[r];
        if ((a > bb) == up) { sel[l] = bb; sel[r] = a; }
      }
      __syncthreads();
    }
  }

  if (tid < 64) {
    const int lane = tid;
    const double THR = 0.45;
    int S = 0, pos = 0;
    while (S < MAXB && pos < TSEL) {
      u64 K = sel[pos + lane];
      bool valid = (K != ~0ULL);
      if (!__any(valid)) break;
      int idx = (int)(K & 0x7FFF);
      double bx1 = 0, by1 = 0, bx2 = 0, by2 = 0, area = 0;
      float sc = 0.f;
      if (valid) {
        const double* bp = boxesd + (size_t)(b * Nn + idx) * 4;
        bx1 = bp[0]; by1 = bp[1]; bx2 = bp[2]; by2 = bp[3];
        area = (bx2 - bx1) * (by2 - by1);
        u64 key49 = (~(K >> 15)) & ((1ULL << 49) - 1);
        u64 e = (key49 >> 45) + 1015ULL;
        u64 mant = (key49 & ((1ULL << 45) - 1)) << 7;
        sc = (float)__longlong_as_double((long long)((e << 52) | mant));
      }
      bool alive = valid;
      for (int k = 0; k < S; ++k) {
        double ltx = fmax(selBox[k][0], bx1), lty = fmax(selBox[k][1], by1);
        double rbx = fmin(selBox[k][2], bx2), rby = fmin(selBox[k][3], by2);
        double w = rbx - ltx; w = w < 0 ? 0 : w;
        double h = rby - lty; h = h < 0 ? 0 : h;
        double inter = w * h;
        double denom = selArea[k] + area - inter + 1e-9;
        if (inter > THR * denom) alive = false;
        if ((k & 7) == 7 && !__any(alive)) break;
      }
      u64 m = __ballot(alive);
      while (m != 0 && S < MAXB) {
        int j = __ffsll((unsigned long long)m) - 1;
        double jx1 = __shfl(bx1, j), jy1 = __shfl(by1, j);
        double jx2 = __shfl(bx2, j), jy2 = __shfl(by2, j);
        double jar = __shfl(area, j);
        float jsc = __shfl(sc, j);
        int jidx = __shfl(idx, j);
        if (lane == 0) {
          selBox[S][0] = jx1; selBox[S][1] = jy1; selBox[S][2] = jx2; selBox[S][3] = jy2;
          selArea[S] = jar; selScore[S] = jsc; selIdx[S] = jidx;
        }
        S++;
        m &= ~(1ULL << j);
        double ltx = fmax(jx1, bx1), lty = fmax(jy1, by1);
        double rbx = fmin(jx2, bx2), rby = fmin(jy2, by2);
        double w = rbx - ltx; w = w < 0 ? 0 : w;
        double h = rby - lty; h = h < 0 ? 0 : h;
        double inter = w * h;
        double denom = jar + area - inter + 1e-9;
        m &= ~__ballot(inter > THR * denom);
      }
      pos += 64;
    }
    if (lane == 0) sS = S;
  }
  __syncthreads();

  const int S = sS;
  float* det_boxes = out;
  float* det_classes = out + Bn * MAXB * 4;
  float* det_scores = out + Bn * MAXB * 4 + Bn * MAXB;
  float* det_num = out + Bn * MAXB * 4 + 2 * Bn * MAXB;
  for (int k = tid; k < MAXB; k += 1024) {
    int o = b * MAXB + k;
    if (k < S) {
      det_boxes[o * 4 + 0] = (float)selBox[k][0];
      det_boxes[o * 4 + 1] = (float)selBox[k][1];
      det_boxes[o * 4 + 2] = (float)selBox[k][2];
      det_boxes[o * 4 + 3] = (float)selBox[k][3];
      det_classes[o] = (float)clsd[b * Nn + selIdx[k]];
      det_scores[o] = selScore[k];
    } else {
      det_boxes[o * 4 + 0] = 0.f; det_boxes[o * 4 + 1] = 0.f;
      det_boxes[o * 4 + 2] = 0.f; det_boxes[o * 4 + 3] = 0.f;
      det_classes[o] = 0.f;
      det_scores[o] = 0.f;
    }
  }
  if (tid == 0) det_num[b] = (float)S;
}

// ============================================================
extern "C" void kernel_launch(void* const* d_in, const int* in_sizes, int n_in,
                              void* d_out, int out_size, void* d_ws, size_t ws_size,
                              hipStream_t stream) {
  const float* logits = (const float*)d_in[0];
  const float* anchors = (const float*)d_in[1];
  float* out = (float*)d_out;
  char* ws = (char*)d_ws;

  double* boxesd = (double*)ws;
  size_t off = (size_t)Bn * Nn * 4 * sizeof(double);
  int* clsd = (int*)(ws + off);  off += (size_t)Bn * Nn * sizeof(int);
  u32* binA = (u32*)(ws + off);  off += (size_t)Bn * Nn * sizeof(u32);
  int* hist = (int*)(ws + off);  off += (size_t)Bn * NBIN * sizeof(int);
  int* Cg   = (int*)(ws + off);  off += (size_t)Bn * sizeof(int);
  int* cntG = (int*)(ws + off);  off += (size_t)Bn * sizeof(int);
  int* clist= (int*)(ws + off);  off += (size_t)Bn * TSEL * sizeof(int);
  u64* ekeys= (u64*)(ws + off);

  hipMemsetAsync(hist, 0, (size_t)Bn * NBIN * sizeof(int), stream);
  hipMemsetAsync(cntG, 0, (size_t)Bn * sizeof(int), stream);
  kk1_score  <<<dim3(1536),     dim3(256),  0, stream>>>(logits, binA, hist);
  kk2_cutoff <<<dim3(Bn),       dim3(256),  0, stream>>>(hist, Cg);
  kk3_compact<<<dim3(Bn * 96),  dim3(256),  0, stream>>>(binA, Cg, cntG, clist);
  kk4_rescore<<<dim3(Bn * 128), dim3(256),  0, stream>>>(logits, anchors, clist, cntG,
                                                         boxesd, clsd, ekeys);
  kk5_nms    <<<dim3(Bn),       dim3(1024), 0, stream>>>(ekeys, boxesd, clsd, out);
}

// Round 6
// 238.826 us; speedup vs baseline: 2.3878x; 2.3878x over previous
//
#include <hip/hip_runtime.h>

#define Bn 32
#define Nn 24564
#define MAXB 200
#define NBIN 2048
#define CH 2048
#define INVK 0xFFFFFFFFu

typedef unsigned long long u64;
typedef unsigned int u32;

// -------- accurate double exp (rel err ~6e-15) -- bit-stable since R2 --------
__device__ inline double fast_exp_d(double x) {
  const double LOG2E = 1.4426950408889634074;
  const double LN2   = 0.69314718055994530942;
  double t = x * LOG2E;
  double fi = floor(t + 0.5);
  double f = (t - fi) * LN2;
  double p = 2.505210838544172e-8;
  p = p * f + 2.755731922398589e-7;
  p = p * f + 2.7557319223985893e-6;
  p = p * f + 2.48015873015873e-5;
  p = p * f + 1.984126984126984e-4;
  p = p * f + 1.3888888888888889e-3;
  p = p * f + 8.333333333333333e-3;
  p = p * f + 4.1666666666666664e-2;
  p = p * f + 1.6666666666666666e-1;
  p = p * f + 0.5;
  p = p * f + 1.0;
  p = p * f + 1.0;
  long long e = (long long)fi;
  return p * __longlong_as_double((e + 1023LL) << 52);
}

__device__ inline double clip01(double v) {
  return v < 0.0 ? 0.0 : (v > 1.0 ? 1.0 : v);
}

// ============================================================
// q1: f32 scoring -> one u32 key per anchor. NO atomics, NO histogram.
// key = ~float_bits(score): ascending key == descending score.
// invalid -> 0xFFFFFFFF. Structure identical to R4's 176us k_score.
// ============================================================
__global__ __launch_bounds__(256) void q1_score(const float* __restrict__ logits,
                                                u32* __restrict__ keyA) {
  __shared__ float lds[64 * 85];
  const int tid = threadIdx.x;
  const int bx = blockIdx.x;
  const int b = bx / 384;
  const int n0 = (bx % 384) << 6;
  int cnt = Nn - n0;
  cnt = cnt > 64 ? 64 : cnt;               // 64 or 52
  const int nf4 = (cnt * 85) >> 2;
  const float4* src = reinterpret_cast<const float4*>(logits + ((size_t)b * Nn + n0) * 85);
  float4* dst = reinterpret_cast<float4*>(lds);
  for (int i = tid; i < nf4; i += 256) dst[i] = src[i];
  __syncthreads();

  const int g = tid >> 2;
  const int s = tid & 3;
  if (g < cnt) {
    const float* row = lds + g * 85;
    float mx = -1e30f; int ai = 1000;
    for (int c = s; c < 81; c += 4) {
      float v = row[4 + c];
      if (v > mx) { mx = v; ai = c; }
    }
    #pragma unroll
    for (int d = 1; d <= 2; d <<= 1) {
      float om = __shfl_xor(mx, d);
      int oi = __shfl_xor(ai, d);
      if (om > mx || (om == mx && oi < ai)) { mx = om; ai = oi; }
    }
    float sum = 0.f;
    for (int c = s; c < 81; c += 4) sum += __expf(row[4 + c] - mx);
    sum += __shfl_xor(sum, 1);
    sum += __shfl_xor(sum, 2);
    if (s == 0) {
      float sc = 1.0f / sum;
      u32 kv = INVK;
      if (ai != 0 && sc >= 0.00985f) kv = ~__float_as_uint(sc);  // margin; exact recheck in q2
      keyA[(size_t)b * Nn + n0 + g] = kv;
    }
  }
}

// ============================================================
// q2: per-image (32 blocks x 1024 thr):
//  LDS histogram of keys -> prefix scan -> complete-bin chunks of <=2048 ->
//  exact f64 rescore (bit-identical order to R2) -> LDS bitonic sort ->
//  greedy NMS with persistent state -> outputs.
// ============================================================
__global__ __launch_bounds__(1024) void q2_selnms(const float* __restrict__ logits,
                                                  const float* __restrict__ anchors,
                                                  const u32* __restrict__ keyA,
                                                  double* __restrict__ boxesd,
                                                  int* __restrict__ clsd,
                                                  float* __restrict__ out) {
  __shared__ int hist[NBIN];        // counts, then inclusive cumsum
  __shared__ int part[1024];
  __shared__ int wsum[16];
  __shared__ int clist[CH];
  __shared__ u64 ekeys[CH];
  __shared__ double selBox[MAXB][4];
  __shared__ double selArea[MAXB];
  __shared__ float selScore[MAXB];
  __shared__ int selIdx[MAXB];
  __shared__ int sBinHi, sCnt, sS;

  const int b = blockIdx.x;
  const int tid = threadIdx.x;
  const u32* kb = keyA + (size_t)b * Nn;

  // --- histogram (bins of key32 top bits; valid keys -> bin in [0,1982)) ---
  for (int i = tid; i < NBIN; i += 1024) hist[i] = 0;
  if (tid == 0) sS = 0;
  __syncthreads();
  for (int i = tid; i < Nn; i += 1024) {
    u32 kv = kb[i];
    u32 bin = (kv - 0xC0000000u) >> 15;    // INVK -> 32767 (skipped)
    if (bin < NBIN) atomicAdd(&hist[bin], 1);
  }
  __syncthreads();

  // --- inclusive prefix scan of hist (each thread owns bins 2t, 2t+1) ---
  int h0 = hist[2 * tid], h1 = hist[2 * tid + 1];
  int v = h0 + h1;
  const int lane = tid & 63, wid = tid >> 6;
  int iv = v;
  #pragma unroll
  for (int d = 1; d < 64; d <<= 1) {
    int t = __shfl_up(iv, d);
    if (lane >= d) iv += t;
  }
  if (lane == 63) wsum[wid] = iv;
  __syncthreads();
  if (tid < 16) {
    int w = wsum[tid];
    #pragma unroll
    for (int d = 1; d < 16; d <<= 1) {
      int t = __shfl_up(w, d);
      if ((int)tid >= d) w += t;
    }
    wsum[tid] = w;
  }
  __syncthreads();
  int excl = iv - v + (wid > 0 ? wsum[wid - 1] : 0);
  hist[2 * tid] = excl + h0;
  hist[2 * tid + 1] = excl + h0 + h1;
  __syncthreads();
  const int totalValid = hist[NBIN - 1];

  // --- chunk loop: complete bins totalling <= CH, NMS continues across chunks ---
  int binLo = -1, scanBase = 0;
  for (;;) {
    if (sS >= MAXB || scanBase >= totalValid) break;
    if (tid == 0) { sBinHi = binLo; sCnt = 0; }
    __syncthreads();
    {
      const int limit = scanBase + CH;
      int loc = -1;
      if (hist[2 * tid] <= limit) loc = 2 * tid;
      if (hist[2 * tid + 1] <= limit) loc = 2 * tid + 1;
      if (loc > binLo) atomicMax(&sBinHi, loc);
    }
    __syncthreads();
    int binHi = sBinHi;
    if (binHi == binLo) binHi = binLo + 1;   // oversized-single-bin fallback (cap below)

    // compact anchors with bin in (binLo, binHi] -> clist (wave-aggregated)
    for (int i0 = 0; i0 < Nn; i0 += 1024) {
      int i = i0 + tid;
      bool pred = false;
      if (i < Nn) {
        u32 kv = kb[i];
        int bin = (int)((kv - 0xC0000000u) >> 15);
        pred = (bin > binLo) && (bin <= binHi);
      }
      u64 m = __ballot(pred);
      int base = 0;
      if ((tid & 63) == 0 && m) base = atomicAdd(&sCnt, (int)__popcll(m));
      base = __shfl(base, 0);
      if (pred) {
        int off = (int)__popcll(m & ((1ULL << (tid & 63)) - 1ULL));
        int p = base + off;
        if (p < CH) clist[p] = i;
      }
    }
    __syncthreads();
    int count = sCnt; count = count > CH ? CH : count;
    for (int i = tid; i < CH; i += 1024) ekeys[i] = ~0ULL;
    __syncthreads();

    // exact f64 rescore (4 lanes/candidate; summation order identical to R2)
    {
      const int g = tid >> 2, s = tid & 3;
      #pragma unroll 1
      for (int pass = 0; pass < CH / 256; ++pass) {
        int slot = pass * 256 + g;
        if (slot < count) {
          const int n = clist[slot];
          const float* row = logits + ((size_t)b * Nn + n) * 85;
          float rv[21];
          float mx = -1e30f; int ai = 1000;
          #pragma unroll
          for (int q = 0; q < 21; ++q) {
            int cc = s + 4 * q;
            float vv = (cc < 81) ? row[4 + cc] : -1e30f;
            rv[q] = vv;
            if (cc < 81 && vv > mx) { mx = vv; ai = cc; }
          }
          #pragma unroll
          for (int d = 1; d <= 2; d <<= 1) {
            float om = __shfl_xor(mx, d);
            int oi = __shfl_xor(ai, d);
            if (om > mx || (om == mx && oi < ai)) { mx = om; ai = oi; }
          }
          double sum = 0.0;
          #pragma unroll
          for (int q = 0; q < 21; ++q) {
            if (s + 4 * q < 81) sum += fast_exp_d((double)rv[q] - (double)mx);
          }
          sum += __shfl_xor(sum, 1);
          sum += __shfl_xor(sum, 2);
          if (s == 0) {
            u64 K = ~0ULL;
            double score = 1.0 / sum;
            if (ai != 0 && score >= 0.01) {
              float4 a4 = reinterpret_cast<const float4*>(anchors)[n];
              double ax1 = a4.x, ay1 = a4.y, ax2 = a4.z, ay2 = a4.w;
              double cx = (ax2 + ax1) * 0.5, cy = (ay2 + ay1) * 0.5;
              double ww = ax2 - ax1, hh = ay2 - ay1;
              double ctrx = (double)row[0] * ww + cx;
              double ctry = (double)row[1] * hh + cy;
              double szx = fast_exp_d((double)row[2]) * ww;
              double szy = fast_exp_d((double)row[3]) * hh;
              double* bp = boxesd + (size_t)(b * Nn + n) * 4;
              bp[0] = clip01(ctrx - szx * 0.5);
              bp[1] = clip01(ctry - szy * 0.5);
              bp[2] = clip01(ctrx + szx * 0.5);
              bp[3] = clip01(ctry + szy * 0.5);
              clsd[b * Nn + n] = ai;
              u64 sb = (u64)__double_as_longlong(score);
              u64 e4 = (sb >> 52) - 1015ULL;
              u64 mant45 = (sb & ((1ULL << 52) - 1)) >> 7;
              u64 flip = (~((e4 << 45) | mant45)) & ((1ULL << 49) - 1);
              K = (flip << 15) | (u64)n;
            }
            ekeys[slot] = K;
          }
        }
      }
    }
    __syncthreads();

    // bitonic sort of CH keys in LDS, ascending (CH/2 == blockDim)
    for (int k = 2; k <= CH; k <<= 1) {
      for (int j = k >> 1; j >= 1; j >>= 1) {
        int l = ((tid & ~(j - 1)) << 1) | (tid & (j - 1));
        int r = l | j;
        bool up = ((l & k) == 0);
        u64 a = ekeys[l], bb = ekeys[r];
        if ((a > bb) == up) { ekeys[l] = bb; ekeys[r] = a; }
        __syncthreads();
      }
    }

    // greedy NMS (wave 0), state persists across chunks via sS/sel*
    if (tid < 64) {
      const double THR = 0.45;
      int S = sS, pos = 0;
      while (S < MAXB && pos < CH) {
        u64 K = ekeys[pos + lane];
        bool valid = (K != ~0ULL);
        if (!__any(valid)) break;
        int idx = (int)(K & 0x7FFF);
        double bx1 = 0, by1 = 0, bx2 = 0, by2 = 0, area = 0;
        float sc = 0.f;
        if (valid) {
          const double* bp = boxesd + (size_t)(b * Nn + idx) * 4;
          bx1 = bp[0]; by1 = bp[1]; bx2 = bp[2]; by2 = bp[3];
          area = (bx2 - bx1) * (by2 - by1);
          u64 key49 = (~(K >> 15)) & ((1ULL << 49) - 1);
          u64 e = (key49 >> 45) + 1015ULL;
          u64 mant = (key49 & ((1ULL << 45) - 1)) << 7;
          sc = (float)__longlong_as_double((long long)((e << 52) | mant));
        }
        bool alive = valid;
        for (int k = 0; k < S; ++k) {
          double ltx = fmax(selBox[k][0], bx1), lty = fmax(selBox[k][1], by1);
          double rbx = fmin(selBox[k][2], bx2), rby = fmin(selBox[k][3], by2);
          double w = rbx - ltx; w = w < 0 ? 0 : w;
          double h = rby - lty; h = h < 0 ? 0 : h;
          double inter = w * h;
          double denom = selArea[k] + area - inter + 1e-9;
          if (inter > THR * denom) alive = false;
          if ((k & 7) == 7 && !__any(alive)) break;
        }
        u64 m = __ballot(alive);
        while (m != 0 && S < MAXB) {
          int j = __ffsll((unsigned long long)m) - 1;
          double jx1 = __shfl(bx1, j), jy1 = __shfl(by1, j);
          double jx2 = __shfl(bx2, j), jy2 = __shfl(by2, j);
          double jar = __shfl(area, j);
          float jsc = __shfl(sc, j);
          int jidx = __shfl(idx, j);
          if (lane == 0) {
            selBox[S][0] = jx1; selBox[S][1] = jy1; selBox[S][2] = jx2; selBox[S][3] = jy2;
            selArea[S] = jar; selScore[S] = jsc; selIdx[S] = jidx;
          }
          S++;
          m &= ~(1ULL << j);
          double ltx = fmax(jx1, bx1), lty = fmax(jy1, by1);
          double rbx = fmin(jx2, bx2), rby = fmin(jy2, by2);
          double w = rbx - ltx; w = w < 0 ? 0 : w;
          double h = rby - lty; h = h < 0 ? 0 : h;
          double inter = w * h;
          double denom = jar + area - inter + 1e-9;
          m &= ~__ballot(inter > THR * denom);
        }
        pos += 64;
      }
      if (lane == 0) sS = S;
    }
    __syncthreads();
    scanBase = hist[binHi];   // inclusive cumsum = total consumed
    binLo = binHi;
  }

  // --- outputs (whole buffer read as f32 by harness) ---
  const int S = sS;
  float* det_boxes = out;
  float* det_classes = out + Bn * MAXB * 4;
  float* det_scores = out + Bn * MAXB * 4 + Bn * MAXB;
  float* det_num = out + Bn * MAXB * 4 + 2 * Bn * MAXB;
  for (int k = tid; k < MAXB; k += 1024) {
    int o = b * MAXB + k;
    if (k < S) {
      det_boxes[o * 4 + 0] = (float)selBox[k][0];
      det_boxes[o * 4 + 1] = (float)selBox[k][1];
      det_boxes[o * 4 + 2] = (float)selBox[k][2];
      det_boxes[o * 4 + 3] = (float)selBox[k][3];
      det_classes[o] = (float)clsd[b * Nn + selIdx[k]];
      det_scores[o] = selScore[k];
    } else {
      det_boxes[o * 4 + 0] = 0.f; det_boxes[o * 4 + 1] = 0.f;
      det_boxes[o * 4 + 2] = 0.f; det_boxes[o * 4 + 3] = 0.f;
      det_classes[o] = 0.f;
      det_scores[o] = 0.f;
    }
  }
  if (tid == 0) det_num[b] = (float)S;
}

// ============================================================
extern "C" void kernel_launch(void* const* d_in, const int* in_sizes, int n_in,
                              void* d_out, int out_size, void* d_ws, size_t ws_size,
                              hipStream_t stream) {
  const float* logits = (const float*)d_in[0];
  const float* anchors = (const float*)d_in[1];
  float* out = (float*)d_out;
  char* ws = (char*)d_ws;

  // ws: boxesd f64[B*N*4] | clsd i32[B*N] | keyA u32[B*N]
  double* boxesd = (double*)ws;
  size_t off = (size_t)Bn * Nn * 4 * sizeof(double);
  int* clsd = (int*)(ws + off);  off += (size_t)Bn * Nn * sizeof(int);
  u32* keyA = (u32*)(ws + off);

  q1_score <<<dim3(Bn * 384), dim3(256),  0, stream>>>(logits, keyA);
  q2_selnms<<<dim3(Bn),       dim3(1024), 0, stream>>>(logits, anchors, keyA,
                                                       boxesd, clsd, out);
}

// Round 7
// 187.915 us; speedup vs baseline: 3.0347x; 1.2709x over previous
//
#include <hip/hip_runtime.h>

#define Bn 32
#define Nn 24564
#define MAXB 200
#define NBIN 2048
#define CH 2048
#define INVK 0xFFFFFFFFu

typedef unsigned long long u64;
typedef unsigned int u32;

// -------- accurate double exp (rel err ~6e-15) -- bit-stable since R2 --------
__device__ inline double fast_exp_d(double x) {
  const double LOG2E = 1.4426950408889634074;
  const double LN2   = 0.69314718055994530942;
  double t = x * LOG2E;
  double fi = floor(t + 0.5);
  double f = (t - fi) * LN2;
  double p = 2.505210838544172e-8;
  p = p * f + 2.755731922398589e-7;
  p = p * f + 2.7557319223985893e-6;
  p = p * f + 2.48015873015873e-5;
  p = p * f + 1.984126984126984e-4;
  p = p * f + 1.3888888888888889e-3;
  p = p * f + 8.333333333333333e-3;
  p = p * f + 4.1666666666666664e-2;
  p = p * f + 1.6666666666666666e-1;
  p = p * f + 0.5;
  p = p * f + 1.0;
  p = p * f + 1.0;
  long long e = (long long)fi;
  return p * __longlong_as_double((e + 1023LL) << 52);
}

__device__ inline double clip01(double v) {
  return v < 0.0 ? 0.0 : (v > 1.0 ? 1.0 : v);
}

// ============================================================
// r1: f32 scoring -> one u32 key per anchor. (proven ~54us, 78% HBM)
// ============================================================
__global__ __launch_bounds__(256) void r1_score(const float* __restrict__ logits,
                                                u32* __restrict__ keyA) {
  __shared__ float lds[64 * 85];
  const int tid = threadIdx.x;
  const int bx = blockIdx.x;
  const int b = bx / 384;
  const int n0 = (bx % 384) << 6;
  int cnt = Nn - n0;
  cnt = cnt > 64 ? 64 : cnt;               // 64 or 52
  const int nf4 = (cnt * 85) >> 2;
  const float4* src = reinterpret_cast<const float4*>(logits + ((size_t)b * Nn + n0) * 85);
  float4* dst = reinterpret_cast<float4*>(lds);
  for (int i = tid; i < nf4; i += 256) dst[i] = src[i];
  __syncthreads();

  const int g = tid >> 2;
  const int s = tid & 3;
  if (g < cnt) {
    const float* row = lds + g * 85;
    float mx = -1e30f; int ai = 1000;
    for (int c = s; c < 81; c += 4) {
      float v = row[4 + c];
      if (v > mx) { mx = v; ai = c; }
    }
    #pragma unroll
    for (int d = 1; d <= 2; d <<= 1) {
      float om = __shfl_xor(mx, d);
      int oi = __shfl_xor(ai, d);
      if (om > mx || (om == mx && oi < ai)) { mx = om; ai = oi; }
    }
    float sum = 0.f;
    for (int c = s; c < 81; c += 4) sum += __expf(row[4 + c] - mx);
    sum += __shfl_xor(sum, 1);
    sum += __shfl_xor(sum, 2);
    if (s == 0) {
      float sc = 1.0f / sum;
      u32 kv = INVK;
      if (ai != 0 && sc >= 0.00985f) kv = ~__float_as_uint(sc);  // margin; exact recheck in r2
      keyA[(size_t)b * Nn + n0 + g] = kv;
    }
  }
}

// ============================================================
// r2: per-image: LDS hist -> scan -> complete-bin chunks -> exact f64
// rescore -> LDS bitonic sort -> MULTI-WAVE greedy NMS -> outputs.
// ============================================================
__global__ __launch_bounds__(1024) void r2_selnms(const float* __restrict__ logits,
                                                  const float* __restrict__ anchors,
                                                  const u32* __restrict__ keyA,
                                                  double* __restrict__ boxesd,
                                                  int* __restrict__ clsd,
                                                  float* __restrict__ out) {
  __shared__ int hist[NBIN];        // counts, then inclusive cumsum
  __shared__ int wsum[16];
  __shared__ int clist[CH];
  __shared__ u64 ekeys[CH];
  __shared__ double bb[64][4];      // current batch candidate boxes
  __shared__ u64 awv[16];           // per-wave alive masks
  __shared__ double selBox[MAXB][4];
  __shared__ double selArea[MAXB];
  __shared__ float selScore[MAXB];
  __shared__ int selIdx[MAXB];
  __shared__ int sBinHi, sCnt, sS;

  const int b = blockIdx.x;
  const int tid = threadIdx.x;
  const int lane = tid & 63, wid = tid >> 6;
  const u32* kb = keyA + (size_t)b * Nn;

  // --- histogram (valid keys -> bin in [0,1982)) ---
  for (int i = tid; i < NBIN; i += 1024) hist[i] = 0;
  if (tid == 0) sS = 0;
  __syncthreads();
  for (int i = tid; i < Nn; i += 1024) {
    u32 kv = kb[i];
    u32 bin = (kv - 0xC0000000u) >> 15;    // INVK -> huge (skipped)
    if (bin < NBIN) atomicAdd(&hist[bin], 1);
  }
  __syncthreads();

  // --- inclusive prefix scan (thread owns bins 2t, 2t+1) ---
  int h0 = hist[2 * tid], h1 = hist[2 * tid + 1];
  int v = h0 + h1;
  int iv = v;
  #pragma unroll
  for (int d = 1; d < 64; d <<= 1) {
    int t = __shfl_up(iv, d);
    if (lane >= d) iv += t;
  }
  if (lane == 63) wsum[wid] = iv;
  __syncthreads();
  if (tid < 16) {
    int w = wsum[tid];
    #pragma unroll
    for (int d = 1; d < 16; d <<= 1) {
      int t = __shfl_up(w, d);
      if ((int)tid >= d) w += t;
    }
    wsum[tid] = w;
  }
  __syncthreads();
  int excl = iv - v + (wid > 0 ? wsum[wid - 1] : 0);
  hist[2 * tid] = excl + h0;
  hist[2 * tid + 1] = excl + h0 + h1;
  __syncthreads();
  const int totalValid = hist[NBIN - 1];

  // --- chunk loop: complete bins totalling <= CH; NMS state persists ---
  int binLo = -1, scanBase = 0;
  for (;;) {
    if (sS >= MAXB || scanBase >= totalValid) break;
    if (tid == 0) { sBinHi = binLo; sCnt = 0; }
    __syncthreads();
    {
      const int limit = scanBase + CH;
      int loc = -1;
      if (hist[2 * tid] <= limit) loc = 2 * tid;
      if (hist[2 * tid + 1] <= limit) loc = 2 * tid + 1;
      if (loc > binLo) atomicMax(&sBinHi, loc);
    }
    __syncthreads();
    int binHi = sBinHi;
    if (binHi == binLo) binHi = binLo + 1;   // oversized-single-bin fallback

    // compact anchors with bin in (binLo, binHi] -> clist
    for (int i0 = 0; i0 < Nn; i0 += 1024) {
      int i = i0 + tid;
      bool pred = false;
      if (i < Nn) {
        u32 kv = kb[i];
        int bin = (int)((kv - 0xC0000000u) >> 15);
        pred = (bin > binLo) && (bin <= binHi);
      }
      u64 m = __ballot(pred);
      int base = 0;
      if (lane == 0 && m) base = atomicAdd(&sCnt, (int)__popcll(m));
      base = __shfl(base, 0);
      if (pred) {
        int off = (int)__popcll(m & ((1ULL << lane) - 1ULL));
        int p = base + off;
        if (p < CH) clist[p] = i;
      }
    }
    __syncthreads();
    int count = sCnt; count = count > CH ? CH : count;
    for (int i = tid; i < CH; i += 1024) ekeys[i] = ~0ULL;
    __syncthreads();

    // exact f64 rescore (4 lanes/candidate; summation order proven since R2)
    {
      const int g = tid >> 2, s = tid & 3;
      #pragma unroll 1
      for (int pass = 0; pass < CH / 256; ++pass) {
        int slot = pass * 256 + g;
        if (slot < count) {
          const int n = clist[slot];
          const float* row = logits + ((size_t)b * Nn + n) * 85;
          float rv[21];
          float mx = -1e30f; int ai = 1000;
          #pragma unroll
          for (int q = 0; q < 21; ++q) {
            int cc = s + 4 * q;
            float vv = (cc < 81) ? row[4 + cc] : -1e30f;
            rv[q] = vv;
            if (cc < 81 && vv > mx) { mx = vv; ai = cc; }
          }
          #pragma unroll
          for (int d = 1; d <= 2; d <<= 1) {
            float om = __shfl_xor(mx, d);
            int oi = __shfl_xor(ai, d);
            if (om > mx || (om == mx && oi < ai)) { mx = om; ai = oi; }
          }
          double sum = 0.0;
          #pragma unroll
          for (int q = 0; q < 21; ++q) {
            if (s + 4 * q < 81) sum += fast_exp_d((double)rv[q] - (double)mx);
          }
          sum += __shfl_xor(sum, 1);
          sum += __shfl_xor(sum, 2);
          if (s == 0) {
            u64 K = ~0ULL;
            double score = 1.0 / sum;
            if (ai != 0 && score >= 0.01) {
              float4 a4 = reinterpret_cast<const float4*>(anchors)[n];
              double ax1 = a4.x, ay1 = a4.y, ax2 = a4.z, ay2 = a4.w;
              double cx = (ax2 + ax1) * 0.5, cy = (ay2 + ay1) * 0.5;
              double ww = ax2 - ax1, hh = ay2 - ay1;
              double ctrx = (double)row[0] * ww + cx;
              double ctry = (double)row[1] * hh + cy;
              double szx = fast_exp_d((double)row[2]) * ww;
              double szy = fast_exp_d((double)row[3]) * hh;
              double* bp = boxesd + (size_t)(b * Nn + n) * 4;
              bp[0] = clip01(ctrx - szx * 0.5);
              bp[1] = clip01(ctry - szy * 0.5);
              bp[2] = clip01(ctrx + szx * 0.5);
              bp[3] = clip01(ctry + szy * 0.5);
              clsd[b * Nn + n] = ai;
              u64 sb = (u64)__double_as_longlong(score);
              u64 e4 = (sb >> 52) - 1015ULL;
              u64 mant45 = (sb & ((1ULL << 52) - 1)) >> 7;
              u64 flip = (~((e4 << 45) | mant45)) & ((1ULL << 49) - 1);
              K = (flip << 15) | (u64)n;
            }
            ekeys[slot] = K;
          }
        }
      }
    }
    __syncthreads();

    // bitonic sort of CH keys in LDS, ascending (CH/2 == blockDim)
    for (int k = 2; k <= CH; k <<= 1) {
      for (int j = k >> 1; j >= 1; j >>= 1) {
        int l = ((tid & ~(j - 1)) << 1) | (tid & (j - 1));
        int r = l | j;
        bool up = ((l & k) == 0);
        u64 a = ekeys[l], bbv = ekeys[r];
        if ((a > bbv) == up) { ekeys[l] = bbv; ekeys[r] = a; }
        __syncthreads();
      }
    }

    // ---- MULTI-WAVE greedy NMS ----
    const double THR = 0.45;
    int pos = 0;
    for (;;) {
      int S = sS;
      if (S >= MAXB || pos >= CH) break;
      u64 K = ekeys[pos + lane];          // same across waves
      bool valid = (K != ~0ULL);
      if (!__any(valid)) break;           // uniform (same data per wave)

      // stage batch boxes into LDS (first 256 threads)
      if (tid < 256) {
        int c = tid >> 2, comp = tid & 3;
        u64 Kc = ekeys[pos + c];
        double vv = 0.0;
        if (Kc != ~0ULL)
          vv = boxesd[(size_t)(b * Nn + (int)(Kc & 0x7FFF)) * 4 + comp];
        bb[c][comp] = vv;
      }
      __syncthreads();

      // phase 1: wave 'wid' checks vs selected slice {wid, wid+16, ...}
      double cx1 = bb[lane][0], cy1 = bb[lane][1];
      double cx2 = bb[lane][2], cy2 = bb[lane][3];
      double carea = (cx2 - cx1) * (cy2 - cy1);
      bool aliveL = true;
      for (int k = wid; k < S; k += 16) {
        double ltx = fmax(selBox[k][0], cx1), lty = fmax(selBox[k][1], cy1);
        double rbx = fmin(selBox[k][2], cx2), rby = fmin(selBox[k][3], cy2);
        double w = rbx - ltx; w = w < 0 ? 0 : w;
        double h = rby - lty; h = h < 0 ? 0 : h;
        double inter = w * h;
        double denom = selArea[k] + carea - inter + 1e-9;
        if (inter > THR * denom) aliveL = false;
      }
      u64 aw = __ballot(aliveL);
      if (lane == 0) awv[wid] = aw;
      __syncthreads();

      // phase 2: wave 0 sequential acceptance (decisions identical to R2)
      if (tid < 64) {
        u64 alive = __ballot(valid);
        #pragma unroll
        for (int w = 0; w < 16; ++w) alive &= awv[w];
        u64 m = alive;
        int Sl = S;
        while (m != 0 && Sl < MAXB) {
          int j = __ffsll((unsigned long long)m) - 1;
          double jx1 = bb[j][0], jy1 = bb[j][1], jx2 = bb[j][2], jy2 = bb[j][3];
          double jar = (jx2 - jx1) * (jy2 - jy1);
          u64 Kj = ekeys[pos + j];
          if (lane == 0) {
            u64 key49 = (~(Kj >> 15)) & ((1ULL << 49) - 1);
            u64 e = (key49 >> 45) + 1015ULL;
            u64 mant = (key49 & ((1ULL << 45) - 1)) << 7;
            selBox[Sl][0] = jx1; selBox[Sl][1] = jy1;
            selBox[Sl][2] = jx2; selBox[Sl][3] = jy2;
            selArea[Sl] = jar;
            selScore[Sl] = (float)__longlong_as_double((long long)((e << 52) | mant));
            selIdx[Sl] = (int)(Kj & 0x7FFF);
          }
          Sl++;
          m &= ~(1ULL << j);
          double ltx = fmax(jx1, cx1), lty = fmax(jy1, cy1);
          double rbx = fmin(jx2, cx2), rby = fmin(jy2, cy2);
          double w = rbx - ltx; w = w < 0 ? 0 : w;
          double h = rby - lty; h = h < 0 ? 0 : h;
          double inter = w * h;
          double denom = jar + carea - inter + 1e-9;
          m &= ~__ballot(inter > THR * denom);
        }
        if (lane == 0) sS = Sl;
      }
      __syncthreads();
      pos += 64;
    }
    __syncthreads();
    scanBase = hist[binHi];   // inclusive cumsum = total consumed
    binLo = binHi;
  }

  // --- outputs (whole buffer read as f32 by harness) ---
  const int S = sS;
  float* det_boxes = out;
  float* det_classes = out + Bn * MAXB * 4;
  float* det_scores = out + Bn * MAXB * 4 + Bn * MAXB;
  float* det_num = out + Bn * MAXB * 4 + 2 * Bn * MAXB;
  for (int k = tid; k < MAXB; k += 1024) {
    int o = b * MAXB + k;
    if (k < S) {
      det_boxes[o * 4 + 0] = (float)selBox[k][0];
      det_boxes[o * 4 + 1] = (float)selBox[k][1];
      det_boxes[o * 4 + 2] = (float)selBox[k][2];
      det_boxes[o * 4 + 3] = (float)selBox[k][3];
      det_classes[o] = (float)clsd[b * Nn + selIdx[k]];
      det_scores[o] = selScore[k];
    } else {
      det_boxes[o * 4 + 0] = 0.f; det_boxes[o * 4 + 1] = 0.f;
      det_boxes[o * 4 + 2] = 0.f; det_boxes[o * 4 + 3] = 0.f;
      det_classes[o] = 0.f;
      det_scores[o] = 0.f;
    }
  }
  if (tid == 0) det_num[b] = (float)S;
}

// ============================================================
extern "C" void kernel_launch(void* const* d_in, const int* in_sizes, int n_in,
                              void* d_out, int out_size, void* d_ws, size_t ws_size,
                              hipStream_t stream) {
  const float* logits = (const float*)d_in[0];
  const float* anchors = (const float*)d_in[1];
  float* out = (float*)d_out;
  char* ws = (char*)d_ws;

  // ws: boxesd f64[B*N*4] | clsd i32[B*N] | keyA u32[B*N]
  double* boxesd = (double*)ws;
  size_t off = (size_t)Bn * Nn * 4 * sizeof(double);
  int* clsd = (int*)(ws + off);  off += (size_t)Bn * Nn * sizeof(int);
  u32* keyA = (u32*)(ws + off);

  r1_score <<<dim3(Bn * 384), dim3(256),  0, stream>>>(logits, keyA);
  r2_selnms<<<dim3(Bn),       dim3(1024), 0, stream>>>(logits, anchors, keyA,
                                                       boxesd, clsd, out);
}